// Round 6
// baseline (498.682 us; speedup 1.0000x reference)
//
#include <hip/hip_runtime.h>

#define NT 512
#define NWAVE 8
#define PE 136      // WxT pitch (bf16 elems)
#define PW1 104     // W1T pitch
#define PH 104      // h0 pitch (cols 80..95 zero pad for K=96)
#define PROBE_REP 8

typedef __attribute__((ext_vector_type(8))) short short8;   // 8 x bf16
typedef __attribute__((ext_vector_type(4))) float f32x4;    // MFMA accumulator

__device__ __forceinline__ unsigned short f2b(float f) {
  unsigned int x = __float_as_uint(f);
  return (unsigned short)((x + 0x7fffu + ((x >> 16) & 1u)) >> 16);
}
__device__ __forceinline__ float b2f(unsigned short u) {
  return __uint_as_float(((unsigned int)u) << 16);
}
__device__ __forceinline__ float sigmoidf(float x) {
  return __builtin_amdgcn_rcpf(1.0f + __expf(-x));
}
__device__ __forceinline__ short8 pack8(float4 a, float4 b) {
  short8 r;
  r[0] = (short)f2b(a.x); r[1] = (short)f2b(a.y); r[2] = (short)f2b(a.z); r[3] = (short)f2b(a.w);
  r[4] = (short)f2b(b.x); r[5] = (short)f2b(b.y); r[6] = (short)f2b(b.z); r[7] = (short)f2b(b.w);
  return r;
}
// aq = bf16( k_f32 * f32(bf16 q) )  — q pre-rounded to bf16 (register diet)
__device__ __forceinline__ short8 pack8qb(float4 a, float4 b, short8 qp) {
  short8 r;
  r[0] = (short)f2b(a.x * b2f((unsigned short)qp[0]));
  r[1] = (short)f2b(a.y * b2f((unsigned short)qp[1]));
  r[2] = (short)f2b(a.z * b2f((unsigned short)qp[2]));
  r[3] = (short)f2b(a.w * b2f((unsigned short)qp[3]));
  r[4] = (short)f2b(b.x * b2f((unsigned short)qp[4]));
  r[5] = (short)f2b(b.y * b2f((unsigned short)qp[5]));
  r[6] = (short)f2b(b.z * b2f((unsigned short)qp[6]));
  r[7] = (short)f2b(b.w * b2f((unsigned short)qp[7]));
  return r;
}

// ---- precompute C[b][h] = b0[h] + sum_e q[b][e] * (W0a + W0c)[e][h] ----
__global__ __launch_bounds__(256, 2) void prep_c(
    const float* __restrict__ q, const float* __restrict__ W0,
    const float* __restrict__ b0, float* __restrict__ C, int B)
{
  __shared__ float Wac[64 * 80];
  __shared__ float qlds[32 * 64];
  const int bbase = blockIdx.x * 32, tid = threadIdx.x;
  for (int idx = tid; idx < 5120; idx += 256) {
    const int e = idx / 80, h = idx - e * 80;
    Wac[idx] = W0[e * 80 + h] + W0[(128 + e) * 80 + h];
  }
  for (int idx = tid; idx < 2048; idx += 256) {
    const int bl = idx >> 6, e = idx & 63;
    const int bg = bbase + bl;
    qlds[idx] = (bg < B) ? q[bg * 64 + e] : 0.0f;
  }
  __syncthreads();
  #pragma unroll
  for (int i = 0; i < 10; ++i) {
    const int idx = tid + i * 256;
    const int bl = idx / 80, h = idx - bl * 80;
    const int bg = bbase + bl;
    if (bg < B) {
      float acc = b0[h];
      #pragma unroll 8
      for (int e = 0; e < 64; ++e) acc += qlds[bl * 64 + e] * Wac[e * 80 + h];
      C[bg * 80 + h] = acc;
    }
  }
}

// ---- main: r2 structure + hoisted epilogue loads + bf16 q frags ----
__global__ __launch_bounds__(NT, 2) void din_attn_main(
    const float* __restrict__ q,
    const float* __restrict__ keys,
    const int* __restrict__ klen,
    const float* __restrict__ W0,
    const float* __restrict__ b0,
    const float* __restrict__ W1,
    const float* __restrict__ b1,
    const float* __restrict__ W2,
    const float* __restrict__ b2,
    float* __restrict__ out,
    const float* __restrict__ Cpre,
    int B)
{
  __shared__ __align__(16) unsigned short WxT[80 * PE];        // 21760 B [h][e]
  __shared__ __align__(16) unsigned short W1T[48 * PW1];       //  9984 B [j][h]
  __shared__ __align__(16) unsigned short h0s[NWAVE][16 * PH]; // 26624 B per-wave [t][h]

  const int tid = threadIdx.x;

  for (int idx = tid; idx < 128 * 80; idx += NT) {
    const int e = idx / 80, h = idx - e * 80;
    const float v = (e < 64)
        ? (W0[(64 + e) * 80 + h] - W0[(128 + e) * 80 + h])
        : W0[(128 + e) * 80 + h];
    WxT[h * PE + e] = f2b(v);
  }
  for (int idx = tid; idx < 48 * PW1; idx += NT) {
    const int j = idx / PW1, h = idx - j * PW1;
    W1T[idx] = (j < 40 && h < 80) ? f2b(W1[h * 40 + j]) : (unsigned short)0;
  }
  {
    const int w0i = tid >> 6, ln = tid & 63;
    for (int i = ln; i < 256; i += 64)
      h0s[w0i][(i >> 4) * PH + 80 + (i & 15)] = 0;
  }
  __syncthreads();   // the ONLY block-wide barrier

  const int wv = __builtin_amdgcn_readfirstlane(tid >> 6);
  const int lane = tid & 63;
  const int lm = lane & 15;
  const int quad = lane >> 4;
  const int b = blockIdx.x * NWAVE + wv;
  if (b >= B) return;

  int L = klen[b];
  L = __builtin_amdgcn_readfirstlane(max(0, min(200, L)));
  unsigned short* h0 = h0s[wv];

  // q fragments pre-packed to bf16 (8 VGPRs instead of 16)
  const float4* q4 = (const float4*)(q + (size_t)b * 64);
  const short8 qpk0 = pack8(q4[quad * 2], q4[quad * 2 + 1]);          // e [8q,8q+8)
  const short8 qpk1 = pack8(q4[8 + quad * 2], q4[8 + quad * 2 + 1]);  // e [32+8q,..)

  float cfv[5];
  if (Cpre != nullptr) {
    #pragma unroll
    for (int nt = 0; nt < 5; ++nt) cfv[nt] = Cpre[b * 80 + nt * 16 + lm];
  } else {
    #pragma unroll
    for (int nt = 0; nt < 5; ++nt) cfv[nt] = b0[nt * 16 + lm];
    for (int e = 0; e < 64; ++e) {
      const float qv = q[(size_t)b * 64 + e];
      #pragma unroll
      for (int nt = 0; nt < 5; ++nt) {
        const int col = nt * 16 + lm;
        cfv[nt] += qv * (W0[e * 80 + col] + W0[(128 + e) * 80 + col]);
      }
    }
  }
  float b1v[3], w2v[3];
  #pragma unroll
  for (int nt = 0; nt < 3; ++nt) {
    const int col = nt * 16 + lm;
    b1v[nt] = (col < 40) ? b1[col] : 0.0f;
    w2v[nt] = (col < 40) ? W2[col] : 0.0f;
  }
  const float b2v = b2[0];
  const short8 z8 = {0, 0, 0, 0, 0, 0, 0, 0};
  const float4 z4 = {0.0f, 0.0f, 0.0f, 0.0f};

  const float* kb = keys + (size_t)b * 12800;
  float wacc = 0.0f;
  const int passes = (L + 15) >> 4;

  float4 k0 = z4, k1 = z4, k2 = z4, k3 = z4;
  if (passes > 0 && lm < L) {
    const float4* kp = (const float4*)(kb + (size_t)lm * 64);
    k0 = kp[quad * 2]; k1 = kp[quad * 2 + 1];
    k2 = kp[8 + quad * 2]; k3 = kp[8 + quad * 2 + 1];
  }

  for (int p = 0; p < passes; ++p) {
    const int t0 = p << 4;
    const int nr = min(16, L - t0);

    // ---- pack set0 from prefetched regs ----
    short8 a0 = pack8(k0, k1), a1 = pack8(k2, k3);
    short8 aq0 = pack8qb(k0, k1, qpk0), aq1 = pack8qb(k2, k3, qpk1);
    if (!((t0 + lm) < L)) { a0 = z8; a1 = z8; aq0 = z8; aq1 = z8; }

    // ---- hoist epilogue loads rows t0..t0+7 (latency hides under L1+L2) ----
    const float* krow = kb + (size_t)t0 * 64 + lane;
    float kvA[8];
    #pragma unroll
    for (int t = 0; t < 8; ++t)
      kvA[t] = kb[(size_t)min(t0 + t, 199) * 64 + lane];

    // ---- depth-1 prefetch of next tile keys ----
    if (p + 1 < passes) {
      const int t = t0 + 16 + lm;
      if (t < L) {
        const float4* kp = (const float4*)(kb + (size_t)t * 64);
        k0 = kp[quad * 2]; k1 = kp[quad * 2 + 1];
        k2 = kp[8 + quad * 2]; k3 = kp[8 + quad * 2 + 1];
      } else { k0 = z4; k1 = z4; k2 = z4; k3 = z4; }
    }

    // ---- layer 1: h0[16x80] = sigmoid(x[16x128] @ Wx + C) ----
    __builtin_amdgcn_s_setprio(1);
    #pragma unroll
    for (int nt = 0; nt < 5; ++nt) {
      const int col = nt * 16 + lm;
      const unsigned short* wr = &WxT[col * PE + quad * 8];
      const short8 w0 = *(const short8*)(wr);
      const short8 w1 = *(const short8*)(wr + 32);
      const short8 w2 = *(const short8*)(wr + 64);
      const short8 w3 = *(const short8*)(wr + 96);
      f32x4 acc;
      acc[0] = cfv[nt]; acc[1] = cfv[nt]; acc[2] = cfv[nt]; acc[3] = cfv[nt];
      acc = __builtin_amdgcn_mfma_f32_16x16x32_bf16(a0,  w0, acc, 0, 0, 0);
      acc = __builtin_amdgcn_mfma_f32_16x16x32_bf16(a1,  w1, acc, 0, 0, 0);
      acc = __builtin_amdgcn_mfma_f32_16x16x32_bf16(aq0, w2, acc, 0, 0, 0);
      acc = __builtin_amdgcn_mfma_f32_16x16x32_bf16(aq1, w3, acc, 0, 0, 0);
      #pragma unroll
      for (int r = 0; r < 4; ++r)
        h0[(quad * 4 + r) * PH + col] = f2b(sigmoidf(acc[r]));
    }
    __builtin_amdgcn_s_setprio(0);

    // ---- layer 2+3: intra-wave h0 roundtrip ----
    const short8 ha0 = *(const short8*)&h0[lm * PH + quad * 8];
    const short8 ha1 = *(const short8*)&h0[lm * PH + 32 + quad * 8];
    const short8 ha2 = *(const short8*)&h0[lm * PH + 64 + quad * 8];
    float pd[4] = {0.0f, 0.0f, 0.0f, 0.0f};
    __builtin_amdgcn_s_setprio(1);
    #pragma unroll
    for (int nt = 0; nt < 3; ++nt) {
      const int col = nt * 16 + lm;
      const unsigned short* wr = &W1T[col * PW1 + quad * 8];
      const short8 wb0 = *(const short8*)(wr);
      const short8 wb1 = *(const short8*)(wr + 32);
      const short8 wb2 = *(const short8*)(wr + 64);
      f32x4 acc;
      acc[0] = b1v[nt]; acc[1] = b1v[nt]; acc[2] = b1v[nt]; acc[3] = b1v[nt];
      acc = __builtin_amdgcn_mfma_f32_16x16x32_bf16(ha0, wb0, acc, 0, 0, 0);
      acc = __builtin_amdgcn_mfma_f32_16x16x32_bf16(ha1, wb1, acc, 0, 0, 0);
      acc = __builtin_amdgcn_mfma_f32_16x16x32_bf16(ha2, wb2, acc, 0, 0, 0);
      #pragma unroll
      for (int r = 0; r < 4; ++r) pd[r] += sigmoidf(acc[r]) * w2v[nt];
    }
    __builtin_amdgcn_s_setprio(0);

    // ---- issue second half of epilogue loads (score-independent) ----
    float kvB[8];
    #pragma unroll
    for (int t = 0; t < 8; ++t)
      kvB[t] = kb[(size_t)min(t0 + 8 + t, 199) * 64 + lane];

    #pragma unroll
    for (int r = 0; r < 4; ++r) {
      pd[r] += __shfl_xor(pd[r], 1);
      pd[r] += __shfl_xor(pd[r], 2);
      pd[r] += __shfl_xor(pd[r], 4);
      pd[r] += __shfl_xor(pd[r], 8);
    }
    float sc[4];
    #pragma unroll
    for (int r = 0; r < 4; ++r) sc[r] = sigmoidf(pd[r] + b2v);

    // ---- epilogue: wacc[e=lane] += score[t] * kv[t], loads pre-issued ----
    #pragma unroll
    for (int t = 0; t < 16; ++t) {
      if (t < nr) {  // wave-uniform
        const float sv = __shfl(sc[t & 3], ((t >> 2) << 4) + lm);
        wacc += sv * ((t < 8) ? kvA[t] : kvB[t - 8]);
      }
    }
    (void)krow;
  }

  out[(size_t)b * 64 + lane] = wacc;
}

// ---- diagnostic probe: main's load+pack skeleton ONLY, repeated 8x ----
// Same grid / launch bounds / LDS footprint (=> same 16 waves/CU regime).
// Measures the global-memory + pack + loop floor t_mem: probe dur = 8*t_mem.
__global__ __launch_bounds__(NT, 2) void mem_probe(
    const float* __restrict__ q,
    const float* __restrict__ keys,
    const int* __restrict__ klen,
    float* __restrict__ dump,
    int B)
{
  __shared__ __align__(16) unsigned char lds_pad[58368];
  volatile unsigned char* vp = lds_pad;
  vp[threadIdx.x] = (unsigned char)threadIdx.x;   // force full LDS allocation

  const int tid = threadIdx.x;
  const int wv = __builtin_amdgcn_readfirstlane(tid >> 6);
  const int lane = tid & 63;
  const int lm = lane & 15;
  const int quad = lane >> 4;
  const int b = blockIdx.x * NWAVE + wv;
  if (b >= B) return;

  int L = klen[b];
  L = __builtin_amdgcn_readfirstlane(max(0, min(200, L)));
  const int passes = (L + 15) >> 4;

  const float4* q4 = (const float4*)(q + (size_t)b * 64);
  const short8 qpk0 = pack8(q4[quad * 2], q4[quad * 2 + 1]);
  const short8 qpk1 = pack8(q4[8 + quad * 2], q4[8 + quad * 2 + 1]);

  const float* kb = keys + (size_t)b * 12800;
  const float4 z4 = {0.0f, 0.0f, 0.0f, 0.0f};
  const short8 z8 = {0, 0, 0, 0, 0, 0, 0, 0};
  float wacc = 0.0f;

  for (int rep = 0; rep < PROBE_REP; ++rep) {
    float4 k0 = z4, k1 = z4, k2 = z4, k3 = z4;
    if (passes > 0 && lm < L) {
      const float4* kp = (const float4*)(kb + (size_t)lm * 64);
      k0 = kp[quad * 2]; k1 = kp[quad * 2 + 1];
      k2 = kp[8 + quad * 2]; k3 = kp[8 + quad * 2 + 1];
    }
    for (int p = 0; p < passes; ++p) {
      const int t0 = p << 4;
      short8 a0 = pack8(k0, k1), a1 = pack8(k2, k3);
      short8 aq0 = pack8qb(k0, k1, qpk0), aq1 = pack8qb(k2, k3, qpk1);
      if (!((t0 + lm) < L)) { a0 = z8; a1 = z8; aq0 = z8; aq1 = z8; }

      float kvA[8];
      #pragma unroll
      for (int t = 0; t < 8; ++t)
        kvA[t] = kb[(size_t)min(t0 + t, 199) * 64 + lane];

      if (p + 1 < passes) {
        const int t = t0 + 16 + lm;
        if (t < L) {
          const float4* kp = (const float4*)(kb + (size_t)t * 64);
          k0 = kp[quad * 2]; k1 = kp[quad * 2 + 1];
          k2 = kp[8 + quad * 2]; k3 = kp[8 + quad * 2 + 1];
        } else { k0 = z4; k1 = z4; k2 = z4; k3 = z4; }
      }

      float kvB[8];
      #pragma unroll
      for (int t = 0; t < 8; ++t)
        kvB[t] = kb[(size_t)min(t0 + 8 + t, 199) * 64 + lane];

      // keep-alive: consume packed frags + all loads (cheap VALU)
      wacc += (float)a0[0] + (float)a1[0] + (float)aq0[0] + (float)aq1[0];
      #pragma unroll
      for (int t = 0; t < 8; ++t) wacc += kvA[t] + kvB[t];
    }
  }
  dump[(size_t)b * 64 + lane] = wacc;
}

extern "C" void kernel_launch(void* const* d_in, const int* in_sizes, int n_in,
                              void* d_out, int out_size, void* d_ws, size_t ws_size,
                              hipStream_t stream) {
  const int B = in_sizes[2];
  const size_t csize = (size_t)B * 80 * sizeof(float);
  const size_t csize_al = (csize + 255) & ~(size_t)255;
  const size_t dumpsz = (size_t)B * 64 * sizeof(float);

  const float* Cpre = nullptr;
  if (ws_size >= csize) {
    float* C = (float*)d_ws;
    prep_c<<<(B + 31) / 32, 256, 0, stream>>>(
        (const float*)d_in[0], (const float*)d_in[3], (const float*)d_in[4], C, B);
    Cpre = C;
  }
  din_attn_main<<<(B + NWAVE - 1) / NWAVE, NT, 0, stream>>>(
      (const float*)d_in[0], (const float*)d_in[1], (const int*)d_in[2],
      (const float*)d_in[3], (const float*)d_in[4], (const float*)d_in[5],
      (const float*)d_in[6], (const float*)d_in[7], (const float*)d_in[8],
      (float*)d_out, Cpre, B);
  // diagnostic probe (skipped if workspace too small)
  if (ws_size >= csize_al + dumpsz) {
    float* dump = (float*)((char*)d_ws + csize_al);
    mem_probe<<<(B + NWAVE - 1) / NWAVE, NT, 0, stream>>>(
        (const float*)d_in[0], (const float*)d_in[1], (const int*)d_in[2],
        dump, B);
  }
}

// Round 7
// 320.326 us; speedup vs baseline: 1.5568x; 1.5568x over previous
//
#include <hip/hip_runtime.h>

#define NT 512
#define NWAVE 8
#define PE 136      // WxT pitch (bf16 elems), 272 B rows: 16B-aligned
#define PW1 104     // W1T pitch
#define PH 104      // h0 pitch (cols 80..95 zero pad for K=96)

typedef __attribute__((ext_vector_type(8))) short short8;   // 8 x bf16
typedef __attribute__((ext_vector_type(4))) float f32x4;    // MFMA accumulator

// DPP xor-add over the 16-lane col group: basis {1,2,7,15}
// quad_perm[1,0,3,2]=0xB1 (xor1), quad_perm[2,3,0,1]=0x4E (xor2),
// row_half_mirror=0x141 (xor7), row_mirror=0x140 (xor15).
#define DPP_ADD(x, ctrl)                                                    \
  ((x) + __uint_as_float(__builtin_amdgcn_mov_dpp(                          \
             __float_as_uint(x), (ctrl), 0xf, 0xf, true)))

__device__ __forceinline__ unsigned short f2b(float f) {
  unsigned int x = __float_as_uint(f);
  return (unsigned short)((x + 0x7fffu + ((x >> 16) & 1u)) >> 16);
}
__device__ __forceinline__ float b2f(unsigned short u) {
  return __uint_as_float(((unsigned int)u) << 16);
}
__device__ __forceinline__ float sigmoidf(float x) {
  return __builtin_amdgcn_rcpf(1.0f + __expf(-x));
}
__device__ __forceinline__ short8 pack8(float4 a, float4 b) {
  short8 r;
  r[0] = (short)f2b(a.x); r[1] = (short)f2b(a.y); r[2] = (short)f2b(a.z); r[3] = (short)f2b(a.w);
  r[4] = (short)f2b(b.x); r[5] = (short)f2b(b.y); r[6] = (short)f2b(b.z); r[7] = (short)f2b(b.w);
  return r;
}
// aq = bf16( k_f32 * f32(bf16 q) )  — q pre-rounded to bf16 (register diet)
__device__ __forceinline__ short8 pack8qb(float4 a, float4 b, short8 qp) {
  short8 r;
  r[0] = (short)f2b(a.x * b2f((unsigned short)qp[0]));
  r[1] = (short)f2b(a.y * b2f((unsigned short)qp[1]));
  r[2] = (short)f2b(a.z * b2f((unsigned short)qp[2]));
  r[3] = (short)f2b(a.w * b2f((unsigned short)qp[3]));
  r[4] = (short)f2b(b.x * b2f((unsigned short)qp[4]));
  r[5] = (short)f2b(b.y * b2f((unsigned short)qp[5]));
  r[6] = (short)f2b(b.z * b2f((unsigned short)qp[6]));
  r[7] = (short)f2b(b.w * b2f((unsigned short)qp[7]));
  return r;
}

// ---- precompute C[b][h] = b0[h] + sum_e q[b][e] * (W0a + W0c)[e][h] ----
__global__ __launch_bounds__(256, 2) void prep_c(
    const float* __restrict__ q, const float* __restrict__ W0,
    const float* __restrict__ b0, float* __restrict__ C, int B)
{
  __shared__ float Wac[64 * 80];
  __shared__ float qlds[32 * 64];
  const int bbase = blockIdx.x * 32, tid = threadIdx.x;
  for (int idx = tid; idx < 5120; idx += 256) {
    const int e = idx / 80, h = idx - e * 80;
    Wac[idx] = W0[e * 80 + h] + W0[(128 + e) * 80 + h];
  }
  for (int idx = tid; idx < 2048; idx += 256) {
    const int bl = idx >> 6, e = idx & 63;
    const int bg = bbase + bl;
    qlds[idx] = (bg < B) ? q[bg * 64 + e] : 0.0f;
  }
  __syncthreads();
  #pragma unroll
  for (int i = 0; i < 10; ++i) {
    const int idx = tid + i * 256;
    const int bl = idx / 80, h = idx - bl * 80;
    const int bg = bbase + bl;
    if (bg < B) {
      float acc = b0[h];
      #pragma unroll 8
      for (int e = 0; e < 64; ++e) acc += qlds[bl * 64 + e] * Wac[e * 80 + h];
      C[bg * 80 + h] = acc;
    }
  }
}

// ---- main: r6 structure + DPP butterfly (no DS) + in-lane float4 epilogue ----
// Per 16-row tile: 0 bpermutes (was 32), 4 hoisted float4 epilogue loads
// (was 16 scalar). Score reduce over the 16 col-lanes runs on the VALU pipe
// via DPP xor-basis {1,2,7,15}; scores never leave the lane that uses them
// (lane (quad,lm) owns rows t0+4q+r, cols 4lm..4lm+3). Cross-quad output
// reduce happens ONCE per batch (xor16/32 shfl), then one float4 store.
__global__ __launch_bounds__(NT, 2) void din_attn_main(
    const float* __restrict__ q,
    const float* __restrict__ keys,
    const int* __restrict__ klen,
    const float* __restrict__ W0,
    const float* __restrict__ b0,
    const float* __restrict__ W1,
    const float* __restrict__ b1,
    const float* __restrict__ W2,
    const float* __restrict__ b2,
    float* __restrict__ out,
    const float* __restrict__ Cpre,
    int B)
{
  __shared__ __align__(16) unsigned short WxT[80 * PE];        // 21760 B [h][e]
  __shared__ __align__(16) unsigned short W1T[48 * PW1];       //  9984 B [j][h]
  __shared__ __align__(16) unsigned short h0s[NWAVE][16 * PH]; // 26624 B per-wave [t][h]

  const int tid = threadIdx.x;

  for (int idx = tid; idx < 128 * 80; idx += NT) {
    const int e = idx / 80, h = idx - e * 80;
    const float v = (e < 64)
        ? (W0[(64 + e) * 80 + h] - W0[(128 + e) * 80 + h])
        : W0[(128 + e) * 80 + h];
    WxT[h * PE + e] = f2b(v);
  }
  for (int idx = tid; idx < 48 * PW1; idx += NT) {
    const int j = idx / PW1, h = idx - j * PW1;
    W1T[idx] = (j < 40 && h < 80) ? f2b(W1[h * 40 + j]) : (unsigned short)0;
  }
  {
    const int w0i = tid >> 6, ln = tid & 63;
    for (int i = ln; i < 256; i += 64)
      h0s[w0i][(i >> 4) * PH + 80 + (i & 15)] = 0;
  }
  __syncthreads();   // the ONLY block-wide barrier

  const int wv = __builtin_amdgcn_readfirstlane(tid >> 6);
  const int lane = tid & 63;
  const int lm = lane & 15;
  const int quad = lane >> 4;
  const int b = blockIdx.x * NWAVE + wv;
  if (b >= B) return;

  int L = klen[b];
  L = __builtin_amdgcn_readfirstlane(max(0, min(200, L)));
  unsigned short* h0 = h0s[wv];

  // q fragments pre-packed to bf16 (8 VGPRs)
  const float4* q4 = (const float4*)(q + (size_t)b * 64);
  const short8 qpk0 = pack8(q4[quad * 2], q4[quad * 2 + 1]);          // e [8q,8q+8)
  const short8 qpk1 = pack8(q4[8 + quad * 2], q4[8 + quad * 2 + 1]);  // e [32+8q,..)

  float cfv[5];
  if (Cpre != nullptr) {
    #pragma unroll
    for (int nt = 0; nt < 5; ++nt) cfv[nt] = Cpre[b * 80 + nt * 16 + lm];
  } else {
    #pragma unroll
    for (int nt = 0; nt < 5; ++nt) cfv[nt] = b0[nt * 16 + lm];
    for (int e = 0; e < 64; ++e) {
      const float qv = q[(size_t)b * 64 + e];
      #pragma unroll
      for (int nt = 0; nt < 5; ++nt) {
        const int col = nt * 16 + lm;
        cfv[nt] += qv * (W0[e * 80 + col] + W0[(128 + e) * 80 + col]);
      }
    }
  }
  float b1v[3], w2v[3];
  #pragma unroll
  for (int nt = 0; nt < 3; ++nt) {
    const int col = nt * 16 + lm;
    b1v[nt] = (col < 40) ? b1[col] : 0.0f;
    w2v[nt] = (col < 40) ? W2[col] : 0.0f;
  }
  const float b2v = b2[0];
  const short8 z8 = {0, 0, 0, 0, 0, 0, 0, 0};
  const float4 z4 = {0.0f, 0.0f, 0.0f, 0.0f};

  const float* kb = keys + (size_t)b * 12800;
  float4 w4 = {0.0f, 0.0f, 0.0f, 0.0f};   // out accumulator: e = 4lm..4lm+3
  const int passes = (L + 15) >> 4;

  float4 k0 = z4, k1 = z4, k2 = z4, k3 = z4;
  if (passes > 0 && lm < L) {
    const float4* kp = (const float4*)(kb + (size_t)lm * 64);
    k0 = kp[quad * 2]; k1 = kp[quad * 2 + 1];
    k2 = kp[8 + quad * 2]; k3 = kp[8 + quad * 2 + 1];
  }

  for (int p = 0; p < passes; ++p) {
    const int t0 = p << 4;

    // ---- pack set0 from prefetched regs ----
    short8 a0 = pack8(k0, k1), a1 = pack8(k2, k3);
    short8 aq0 = pack8qb(k0, k1, qpk0), aq1 = pack8qb(k2, k3, qpk1);
    if (!((t0 + lm) < L)) { a0 = z8; a1 = z8; aq0 = z8; aq1 = z8; }

    // ---- hoist epilogue loads: rows t0+4q+r, cols 4lm..4lm+3 (L1-hot) ----
    float4 kv[4];
    #pragma unroll
    for (int r = 0; r < 4; ++r)
      kv[r] = *(const float4*)(kb + (size_t)min(t0 + 4 * quad + r, 199) * 64 + 4 * lm);

    // ---- depth-1 prefetch of next tile keys ----
    if (p + 1 < passes) {
      const int t = t0 + 16 + lm;
      if (t < L) {
        const float4* kp = (const float4*)(kb + (size_t)t * 64);
        k0 = kp[quad * 2]; k1 = kp[quad * 2 + 1];
        k2 = kp[8 + quad * 2]; k3 = kp[8 + quad * 2 + 1];
      } else { k0 = z4; k1 = z4; k2 = z4; k3 = z4; }
    }

    // ---- layer 1: h0[16x80] = sigmoid(x[16x128] @ Wx + C) ----
    __builtin_amdgcn_s_setprio(1);
    #pragma unroll
    for (int nt = 0; nt < 5; ++nt) {
      const int col = nt * 16 + lm;
      const unsigned short* wr = &WxT[col * PE + quad * 8];
      const short8 w0 = *(const short8*)(wr);
      const short8 w1 = *(const short8*)(wr + 32);
      const short8 w2 = *(const short8*)(wr + 64);
      const short8 w3 = *(const short8*)(wr + 96);
      f32x4 acc;
      acc[0] = cfv[nt]; acc[1] = cfv[nt]; acc[2] = cfv[nt]; acc[3] = cfv[nt];
      acc = __builtin_amdgcn_mfma_f32_16x16x32_bf16(a0,  w0, acc, 0, 0, 0);
      acc = __builtin_amdgcn_mfma_f32_16x16x32_bf16(a1,  w1, acc, 0, 0, 0);
      acc = __builtin_amdgcn_mfma_f32_16x16x32_bf16(aq0, w2, acc, 0, 0, 0);
      acc = __builtin_amdgcn_mfma_f32_16x16x32_bf16(aq1, w3, acc, 0, 0, 0);
      #pragma unroll
      for (int r = 0; r < 4; ++r)
        h0[(quad * 4 + r) * PH + col] = f2b(sigmoidf(acc[r]));
    }
    __builtin_amdgcn_s_setprio(0);

    // ---- layer 2+3: intra-wave h0 roundtrip ----
    const short8 ha0 = *(const short8*)&h0[lm * PH + quad * 8];
    const short8 ha1 = *(const short8*)&h0[lm * PH + 32 + quad * 8];
    const short8 ha2 = *(const short8*)&h0[lm * PH + 64 + quad * 8];
    float pd[4] = {0.0f, 0.0f, 0.0f, 0.0f};
    __builtin_amdgcn_s_setprio(1);
    #pragma unroll
    for (int nt = 0; nt < 3; ++nt) {
      const int col = nt * 16 + lm;
      const unsigned short* wr = &W1T[col * PW1 + quad * 8];
      const short8 wb0 = *(const short8*)(wr);
      const short8 wb1 = *(const short8*)(wr + 32);
      const short8 wb2 = *(const short8*)(wr + 64);
      f32x4 acc;
      acc[0] = b1v[nt]; acc[1] = b1v[nt]; acc[2] = b1v[nt]; acc[3] = b1v[nt];
      acc = __builtin_amdgcn_mfma_f32_16x16x32_bf16(ha0, wb0, acc, 0, 0, 0);
      acc = __builtin_amdgcn_mfma_f32_16x16x32_bf16(ha1, wb1, acc, 0, 0, 0);
      acc = __builtin_amdgcn_mfma_f32_16x16x32_bf16(ha2, wb2, acc, 0, 0, 0);
      #pragma unroll
      for (int r = 0; r < 4; ++r) pd[r] += sigmoidf(acc[r]) * w2v[nt];
    }
    __builtin_amdgcn_s_setprio(0);

    // ---- reduce over the 16 col-lanes on the VALU pipe (DPP, no DS) ----
    #pragma unroll
    for (int r = 0; r < 4; ++r) {
      pd[r] = DPP_ADD(pd[r], 0xB1);    // xor 1
      pd[r] = DPP_ADD(pd[r], 0x4E);    // xor 2
      pd[r] = DPP_ADD(pd[r], 0x141);   // xor 7  (row_half_mirror)
      pd[r] = DPP_ADD(pd[r], 0x140);   // xor 15 (row_mirror)
    }
    // scores stay in-lane: lane (quad,lm) owns rows t0+4q+r
    float sc[4];
    #pragma unroll
    for (int r = 0; r < 4; ++r) {
      const int ta = t0 + 4 * quad + r;
      sc[r] = (ta < L) ? sigmoidf(pd[r] + b2v) : 0.0f;
    }

    // ---- epilogue: w4[e=4lm..+3] += sc[r] * keys[t0+4q+r][4lm..+3] ----
    #pragma unroll
    for (int r = 0; r < 4; ++r) {
      w4.x += sc[r] * kv[r].x; w4.y += sc[r] * kv[r].y;
      w4.z += sc[r] * kv[r].z; w4.w += sc[r] * kv[r].w;
    }
  }

  // ---- once per batch: sum the 4 quads' disjoint row-sets, one store ----
  w4.x += __shfl_xor(w4.x, 16); w4.y += __shfl_xor(w4.y, 16);
  w4.z += __shfl_xor(w4.z, 16); w4.w += __shfl_xor(w4.w, 16);
  w4.x += __shfl_xor(w4.x, 32); w4.y += __shfl_xor(w4.y, 32);
  w4.z += __shfl_xor(w4.z, 32); w4.w += __shfl_xor(w4.w, 32);
  if (lane < 16)
    *(float4*)(out + (size_t)b * 64 + 4 * lm) = w4;
}

extern "C" void kernel_launch(void* const* d_in, const int* in_sizes, int n_in,
                              void* d_out, int out_size, void* d_ws, size_t ws_size,
                              hipStream_t stream) {
  const int B = in_sizes[2];
  const float* Cpre = nullptr;
  if (ws_size >= (size_t)B * 80 * sizeof(float)) {
    float* C = (float*)d_ws;
    prep_c<<<(B + 31) / 32, 256, 0, stream>>>(
        (const float*)d_in[0], (const float*)d_in[3], (const float*)d_in[4], C, B);
    Cpre = C;
  }
  din_attn_main<<<(B + NWAVE - 1) / NWAVE, NT, 0, stream>>>(
      (const float*)d_in[0], (const float*)d_in[1], (const int*)d_in[2],
      (const float*)d_in[3], (const float*)d_in[4], (const float*)d_in[5],
      (const float*)d_in[6], (const float*)d_in[7], (const float*)d_in[8],
      (float*)d_out, Cpre, B);
}